// Round 9
// baseline (75.408 us; speedup 1.0000x reference)
//
#include <hip/hip_runtime.h>
#include <math.h>

#define NN 8192
#define DIM 128
#define NG 512                        // 16-row strips
#define NCT 128                       // 64-col tiles per row
#define NITEMS (NG * 16)              // 8192 (strip, phase) work items
#define NBLOCKS 768
#define NWT (NBLOCKS * 4)             // 3072 waves

typedef short bf16x8 __attribute__((ext_vector_type(8)));
typedef float f32x4 __attribute__((ext_vector_type(4)));

__device__ inline unsigned short f2bf(float x) {
    unsigned u = __float_as_uint(x);
    unsigned r = u + 0x7FFFu + ((u >> 16) & 1u);  // RNE
    return (unsigned short)(r >> 16);
}

// ---------------------------------------------------------------------------
// Kernel 0: pack mapping into MFMA-fragment-order bf16 chunks (1KB/wave-load).
// Chunk W = g*4+kq: rows g*16+(l&15), k = kq*32+(l>>4)*8, lane l's 16B at l*16.
// ---------------------------------------------------------------------------
__global__ void pack_kernel(const float* __restrict__ m, unsigned short* __restrict__ buf2) {
    const int t = threadIdx.x, l = t & 63;
    const int W = blockIdx.x * 4 + (t >> 6);
    const int g = W >> 2, kq = W & 3;
    const int row = g * 16 + (l & 15);
    const int k0 = kq * 32 + (l >> 4) * 8;
    const float* src = m + (size_t)row * DIM + k0;
    float4 v0 = *reinterpret_cast<const float4*>(src);
    float4 v1 = *reinterpret_cast<const float4*>(src + 4);
    float f[8] = {v0.x, v0.y, v0.z, v0.w, v1.x, v1.y, v1.z, v1.w};
    union { ushort4 u4[2]; unsigned short us[8]; } o;
#pragma unroll
    for (int q = 0; q < 8; ++q) o.us[q] = f2bf(f[q]);
    unsigned short* dst = buf2 + (size_t)W * 512 + l * 8;
    *reinterpret_cast<ushort4*>(dst) = o.u4[0];
    *reinterpret_cast<ushort4*>(dst + 4) = o.u4[1];
}

// ---------------------------------------------------------------------------
// Kernel 1: exact fp32 row norms
// ---------------------------------------------------------------------------
__global__ void sq_kernel(const float* __restrict__ mapping, float* __restrict__ sq) {
    int i = blockIdx.x * blockDim.x + threadIdx.x;
    if (i < NN) {
        const float4* row = reinterpret_cast<const float4*>(mapping + (size_t)i * DIM);
        float s = 0.f;
#pragma unroll
        for (int q = 0; q < DIM / 4; ++q) {
            float4 v = row[q];
            s += v.x * v.x + v.y * v.y + v.z * v.z + v.w * v.w;
        }
        sq[i] = s;
    }
}

// ---------------------------------------------------------------------------
// Kernel 2: 16-row strip streaming. Work item = (strip g, phase p): tiles
// cj = (g>>2)+p, +16, +32, ... (16 phases interleave per strip).
//  - acc layout of mfma(b,a) matches row-major D: NO transpose, NO LDS.
//  - each wave = 16 parallel sequential DRAM row-streams (256B/row/step).
//  - D(t+1)+sqb(t+1) issued AFTER B(t): B-waits never drain them (in-order
//    vmcnt), so the D stream stays in flight through each step's compute.
//  - FIX vs r8: deterministic wave reduction of psum before lane 0 writes
//    partials[item] (r8 had all 64 lanes racing one scalar -> 1/64 of sum).
// ---------------------------------------------------------------------------
__global__ __launch_bounds__(256, 3) void dist_kernel(const unsigned short* __restrict__ buf2,
                                                      const float* __restrict__ D,
                                                      const float* __restrict__ sq,
                                                      float* __restrict__ partials) {
    const int t = threadIdx.x, l = t & 63;
    const int W = blockIdx.x * 4 + (t >> 6);

    const int l15 = l & 15;
    const int colq = (l >> 4) * 4;    // col offset within a 16-col subtile

    int item = W;
    while (item < NITEMS) {
        const int g = item >> 4, p = item & 15;
        int cj = (g >> 2) + p;
        if (cj >= NCT) {
            if (l == 0) partials[item] = 0.f;
            item += NWT;
            continue;
        }

        const int i_row = g * 16 + l15;
        const int cdiag = g >> 2;

        // ---- A fragments (16 VGPR) + sqa, once per item ----
        bf16x8 af[4];
#pragma unroll
        for (int kq = 0; kq < 4; ++kq)
            af[kq] = *(const bf16x8*)(buf2 + (size_t)(g * 4 + kq) * 512 + l * 8);
        const float sa = sq[i_row];

        // ---- first tile's D + sqb prefetch ----
        f32x4 dc[4], sbc[4];
#pragma unroll
        for (int s = 0; s < 4; ++s) {
            dc[s] = *reinterpret_cast<const f32x4*>(D + (size_t)i_row * NN + cj * 64 + s * 16 + colq);
            sbc[s] = *reinterpret_cast<const f32x4*>(sq + cj * 64 + s * 16 + colq);
        }

        float psum = 0.f;
        for (; cj < NCT; cj += 16) {
            const int ncj = cj + 16;

            // ---- B fragments for this 64-col tile (L2-resident pack) ----
            bf16x8 bfr[4][4];  // [sub][kq]
#pragma unroll
            for (int s = 0; s < 4; ++s)
#pragma unroll
                for (int kq = 0; kq < 4; ++kq)
                    bfr[s][kq] = *(const bf16x8*)(buf2 + (size_t)((cj * 4 + s) * 4 + kq) * 512 + l * 8);

            // ---- D + sqb for NEXT tile (issued after B: stays in flight) ----
            f32x4 dn[4], sbn[4];
            if (ncj < NCT) {
#pragma unroll
                for (int s = 0; s < 4; ++s) {
                    dn[s] = *reinterpret_cast<const f32x4*>(D + (size_t)i_row * NN + ncj * 64 + s * 16 + colq);
                    sbn[s] = *reinterpret_cast<const f32x4*>(sq + ncj * 64 + s * 16 + colq);
                }
            }

            // ---- 4 subtiles: 4 MFMA each, epilogue straight from registers ----
#pragma unroll
            for (int s = 0; s < 4; ++s) {
                f32x4 acc = {};
#pragma unroll
                for (int kq = 0; kq < 4; ++kq)
                    acc = __builtin_amdgcn_mfma_f32_16x16x32_bf16(bfr[s][kq], af[kq], acc, 0, 0, 0);
                if (cj != cdiag) {
#pragma unroll
                    for (int r = 0; r < 4; ++r) {
                        float d2 = fmaf(-2.f, acc[r], sa + sbc[s][r]);
                        float d = sqrtf(fmaxf(d2, 0.f));
                        float Dv = dc[s][r];
                        psum += __fdividef(fabsf(d - Dv), Dv);
                    }
                } else {
#pragma unroll
                    for (int r = 0; r < 4; ++r) {
                        const int j = cj * 64 + s * 16 + colq + r;
                        if (j > i_row) {
                            float d2 = fmaf(-2.f, acc[r], sa + sbc[s][r]);
                            float d = sqrtf(fmaxf(d2, 0.f));
                            float Dv = dc[s][r];
                            psum += __fdividef(fabsf(d - Dv), Dv);
                        }
                    }
                }
            }

            // ---- rotate pipeline ----
            if (ncj < NCT) {
#pragma unroll
                for (int s = 0; s < 4; ++s) { dc[s] = dn[s]; sbc[s] = sbn[s]; }
            }
        }

        // ---- deterministic wave reduction (THE r8 fix) ----
        for (int off = 32; off > 0; off >>= 1) psum += __shfl_down(psum, off, 64);
        if (l == 0) partials[item] = 2.f * psum;  // all counted pairs are i<j

        item += NWT;
    }
}

// ---------------------------------------------------------------------------
// Kernel 3: deterministic final reduction over 8192 item partials
// ---------------------------------------------------------------------------
__global__ void reduce_kernel(const float* __restrict__ partials, float* __restrict__ out) {
    __shared__ double sm[256];
    const int t = threadIdx.x;
    double s = 0.0;
    for (int i = t; i < NITEMS; i += 256) s += (double)partials[i];
    sm[t] = s;
    __syncthreads();
    for (int off = 128; off > 0; off >>= 1) {
        if (t < off) sm[t] += sm[t + off];
        __syncthreads();
    }
    if (t == 0) out[0] = (float)(sm[0] / ((double)NN * (double)NN - (double)NN));
}

// ---------------------------------------------------------------------------
extern "C" void kernel_launch(void* const* d_in, const int* in_sizes, int n_in,
                              void* d_out, int out_size, void* d_ws, size_t ws_size,
                              hipStream_t stream) {
    const float* mapping = (const float*)d_in[0];
    const float* D       = (const float*)d_in[1];
    float* out = (float*)d_out;

    unsigned short* buf2 = (unsigned short*)d_ws;        // NN*DIM bf16 = 2 MiB
    float* sq            = (float*)(buf2 + NN * DIM);    // NN floats
    float* partials      = sq + NN;                      // NITEMS floats

    pack_kernel<<<512, 256, 0, stream>>>(mapping, buf2);
    sq_kernel<<<NN / 256, 256, 0, stream>>>(mapping, sq);
    dist_kernel<<<NBLOCKS, 256, 0, stream>>>(buf2, D, sq, partials);
    reduce_kernel<<<1, 256, 0, stream>>>(partials, out);
}